// Round 5
// baseline (658.384 us; speedup 1.0000x reference)
//
#include <hip/hip_runtime.h>
#include <hip/hip_bf16.h>
#include <stdint.h>

#define N_NODES 50000
#define N_EDGES 800000
#define IN_DIM 64
#define HID 128
#define OUT_DIM 64
#define T_HIST 8

typedef __attribute__((ext_vector_type(8))) short short8;
typedef __attribute__((ext_vector_type(4))) float f32x4;
typedef __attribute__((ext_vector_type(4))) unsigned short us4;

__device__ __forceinline__ unsigned short f2bf(float x) {
  unsigned int u = __builtin_bit_cast(unsigned int, x);
  unsigned int r = (u + 0x7FFFu + ((u >> 16) & 1u)) >> 16;
  return (unsigned short)r;
}
__device__ __forceinline__ us4 cvt4(float4 f) {
  unsigned int lo, hi;
  asm("v_cvt_pk_bf16_f32 %0, %1, %2" : "=v"(lo) : "v"(f.x), "v"(f.y));
  asm("v_cvt_pk_bf16_f32 %0, %1, %2" : "=v"(hi) : "v"(f.z), "v"(f.w));
  struct { unsigned int a, b; } s{lo, hi};
  return __builtin_bit_cast(us4, s);
}
__device__ __forceinline__ short8 cvt8(float4 a, float4 b) {
  unsigned int w0, w1, w2, w3;
  asm("v_cvt_pk_bf16_f32 %0, %1, %2" : "=v"(w0) : "v"(a.x), "v"(a.y));
  asm("v_cvt_pk_bf16_f32 %0, %1, %2" : "=v"(w1) : "v"(a.z), "v"(a.w));
  asm("v_cvt_pk_bf16_f32 %0, %1, %2" : "=v"(w2) : "v"(b.x), "v"(b.y));
  asm("v_cvt_pk_bf16_f32 %0, %1, %2" : "=v"(w3) : "v"(b.z), "v"(b.w));
  struct { unsigned int a, b, c, d; } s{w0, w1, w2, w3};
  return __builtin_bit_cast(short8, s);
}
// sigmoid/tanh via exp2+rcp; safe at +-inf
__device__ __forceinline__ float sigm(float x) {
  float e = __builtin_amdgcn_exp2f(-1.4426950408889634f * x);
  return __builtin_amdgcn_rcpf(1.f + e);
}
__device__ __forceinline__ float tanh_f(float x) {
  float e = __builtin_amdgcn_exp2f(2.8853900817779268f * x);
  return 1.f - 2.f * __builtin_amdgcn_rcpf(e + 1.f);
}

// ---------------- prepack (+ zero cnt): fragment-ordered bf16 weights ----------------
// Wt2: F = q*32 + g*8 + kk; value = Wcomb[k = kk*32+(lane>>4)*8+i][c = g*128 + q*16 + (lane&15)]
// Wc2: F = cb*4 + kk; value = W_cls[k][col = cb*16 + (lane&15)]
__global__ void prepack_kernel(const float* __restrict__ w_ih, const float* __restrict__ w_hh,
                               const float* __restrict__ W_cls,
                               unsigned short* __restrict__ Wt2, unsigned short* __restrict__ Wc2,
                               int* __restrict__ cnt) {
  int tid = blockIdx.x * blockDim.x + threadIdx.x;
  int stride = gridDim.x * blockDim.x;
  for (int i = tid; i < N_NODES; i += stride) cnt[i] = 0;
  for (int idx = tid; idx < 256 * 512; idx += stride) {
    int i = idx & 7;
    int lane = (idx >> 3) & 63;
    int F = idx >> 9;
    int q = F >> 5, g = (F >> 3) & 3, kk = F & 7;
    int c = g * 128 + q * 16 + (lane & 15);
    int k = kk * 32 + (lane >> 4) * 8 + i;
    float v = (k < 128) ? w_ih[k * 512 + c] : w_hh[(k - 128) * 512 + c];
    Wt2[idx] = f2bf(v);
  }
  for (int idx = tid; idx < 16 * 512; idx += stride) {
    int i = idx & 7;
    int lane = (idx >> 3) & 63;
    int F = idx >> 9;
    int cb = F >> 2, kk = F & 3;
    int col = cb * 16 + (lane & 15);
    int k = kk * 32 + (lane >> 4) * 8 + i;
    Wc2[idx] = f2bf(W_cls[k * 64 + col]);
  }
}

// ---------------- CSR build ----------------
__global__ void count_kernel(const int* __restrict__ dst, int* __restrict__ cnt) {
  int e = blockIdx.x * blockDim.x + threadIdx.x;
  if (e < N_EDGES) atomicAdd(&cnt[dst[e]], 1);
}

// fused scan: single block, 1024 threads, chunk 52
__global__ __launch_bounds__(1024) void scan_kernel(const int* __restrict__ cnt,
                                                    int* __restrict__ rowstart,
                                                    int* __restrict__ cursor) {
  __shared__ int sh[1024];
  int tid = threadIdx.x;
  const int C = 52;
  int b0 = tid * C;
  int tsum = 0;
  for (int j = 0; j < C; j++) {
    int i = b0 + j;
    if (i < N_NODES) tsum += cnt[i];
  }
  sh[tid] = tsum;
  __syncthreads();
  int val = tsum;
  for (int off = 1; off < 1024; off <<= 1) {
    int x = (tid >= off) ? sh[tid - off] : 0;
    __syncthreads();
    val += x;
    sh[tid] = val;
    __syncthreads();
  }
  int run = val - tsum;  // exclusive prefix
  for (int j = 0; j < C; j++) {
    int i = b0 + j;
    if (i < N_NODES) { rowstart[i] = run; cursor[i] = run; run += cnt[i]; }
  }
}

__global__ void fill_kernel(const int* __restrict__ src, const int* __restrict__ dst,
                            int* __restrict__ cursor, int* __restrict__ esrc) {
  int e = blockIdx.x * blockDim.x + threadIdx.x;
  if (e < N_EDGES) {
    int d = dst[e];
    int pos = atomicAdd(&cursor[d], 1);
    esrc[pos] = src[e];
  }
}

// ---------------- h_struct = nf@W_self + mean_neigh@W_neigh + b (fused gather) ----------------
#define HS_TILE 32
__global__ __launch_bounds__(512) void hstruct_kernel(
    const float* __restrict__ nf, const int* __restrict__ esrc,
    const int* __restrict__ rowstart, const int* __restrict__ cnt,
    const float* __restrict__ Wself, const float* __restrict__ Wneigh, const float* __restrict__ bs,
    float* __restrict__ hstruct) {
  __shared__ float s_nf[HS_TILE][IN_DIM + 1];
  __shared__ float s_hn[HS_TILE][IN_DIM + 1];
  int tid = threadIdx.x;
  int node0 = blockIdx.x * HS_TILE;
  for (int i = tid; i < HS_TILE * IN_DIM; i += 512) {
    int r = i >> 6, k = i & 63;
    int node = node0 + r;
    s_nf[r][k] = (node < N_NODES) ? nf[node * 64 + k] : 0.f;
  }
  int wv = tid >> 6, lane = tid & 63;
  for (int r = wv; r < HS_TILE; r += 8) {   // 8 waves -> 4 rows each
    int node = node0 + r;
    float a0 = 0.f, a1 = 0.f, a2 = 0.f, a3 = 0.f;
    int n = 0;
    if (node < N_NODES) {
      n = cnt[node];
      int st = rowstart[node];
      int j = 0;
      for (; j + 4 <= n; j += 4) {
        int s0 = esrc[st + j], s1 = esrc[st + j + 1];
        int s2 = esrc[st + j + 2], s3 = esrc[st + j + 3];
        a0 += nf[s0 * 64 + lane];
        a1 += nf[s1 * 64 + lane];
        a2 += nf[s2 * 64 + lane];
        a3 += nf[s3 * 64 + lane];
      }
      for (; j < n; j++) a0 += nf[esrc[st + j] * 64 + lane];
    }
    s_hn[r][lane] = (a0 + a1 + a2 + a3) * __builtin_amdgcn_rcpf(fmaxf((float)n, 1.f));
  }
  __syncthreads();
  int r = tid & 31;
  int c0 = (tid >> 5) * 8;   // 16 col-groups x 8 cols
  float accs[8];
  #pragma unroll
  for (int i = 0; i < 8; i++) accs[i] = 0.f;
  for (int k = 0; k < IN_DIM; k++) {
    float a = s_nf[r][k];
    float b = s_hn[r][k];
    const float4* ws = (const float4*)&Wself[k * HID + c0];
    const float4* wn = (const float4*)&Wneigh[k * HID + c0];
    #pragma unroll
    for (int q2 = 0; q2 < 2; q2++) {
      float4 w1 = ws[q2]; float4 w2 = wn[q2];
      accs[q2*4+0] += a * w1.x + b * w2.x;
      accs[q2*4+1] += a * w1.y + b * w2.y;
      accs[q2*4+2] += a * w1.z + b * w2.z;
      accs[q2*4+3] += a * w1.w + b * w2.w;
    }
  }
  int node = node0 + r;
  if (node < N_NODES) {
    #pragma unroll
    for (int i = 0; i < 8; i++)
      hstruct[(size_t)node * HID + c0 + i] = accs[i] + bs[c0 + i];
  }
}

// ---------------- fused LSTM + classifier: 1024 thr = 16 waves, gate-split ----------------
// Wave (q = w>>1, h = w&1): cols jj in [16q,16q+16), gates {2h, 2h+1}. Bfr = 64 VGPR.
// h=1 publishes g,o via fp32 LDS Gbuf; h=0 owns c_st and does cell updates; h=1 stages x(t+1).
#define LB 32
__global__ __launch_bounds__(1024, 4) void lstm_kernel(
    const float* __restrict__ hist,          // [N][8][128] f32
    const unsigned short* __restrict__ Wt2,  // frag-ordered bf16
    const unsigned short* __restrict__ Wc2,  // frag-ordered bf16
    const float* __restrict__ b_lstm,        // [512]
    const float* __restrict__ hstruct,       // [N][128]
    const float* __restrict__ b_cls,         // [64]
    float* __restrict__ out)                 // [N][64]
{
  __shared__ alignas(16) unsigned short Abuf[2][LB * 256];  // 2 x 16KB
  __shared__ alignas(16) float Gbuf[HID * 64];              // 32KB

  const int tid = threadIdx.x;
  const int lane = tid & 63;
  const int w = tid >> 6;      // 0..15
  const int q = w >> 1;        // 0..7
  const int h = w & 1;
  const int l15 = lane & 15;
  const int l4 = lane >> 4;
  const int base = blockIdx.x * LB;
  const int jj = q * 16 + l15;

  // persistent B fragments: 2 gates x 8 kk = 64 VGPR
  short8 Bfr[2][8];
  #pragma unroll
  for (int gg = 0; gg < 2; gg++)
    #pragma unroll
    for (int kk = 0; kk < 8; kk++)
      Bfr[gg][kk] = *(const short8*)&Wt2[((q * 32 + (2 * h + gg) * 8 + kk) * 64 + lane) * 8];

  const float bi  = b_lstm[jj];
  const float bf_ = b_lstm[128 + jj];
  const float bg  = b_lstm[256 + jj];
  const float bo  = b_lstm[384 + jj];

  float c_st[8];
  #pragma unroll
  for (int i = 0; i < 8; i++) c_st[i] = 0.f;

  // prologue: zero h-region + stage x(0); 2 threads per short8 unit
  {
    int u = tid >> 1, sub = tid & 1;
    int srow = u >> 4, skb = u & 15;
    us4 z = {0, 0, 0, 0};
    *(us4*)&Abuf[0][srow * 256 + 128 + skb * 8 + sub * 4] = z;
    int node = base + srow;
    float4 x0 = make_float4(0.f, 0.f, 0.f, 0.f);
    if (node < N_NODES)
      x0 = *(const float4*)&hist[(size_t)node * (T_HIST * HID) + skb * 8 + sub * 4];
    int ssb = (skb & 8) | ((skb & 7) ^ (srow & 7));
    *(us4*)&Abuf[0][srow * 256 + ssb * 8 + sub * 4] = cvt4(x0);
  }
  __syncthreads();

  float4 xpa = make_float4(0.f,0.f,0.f,0.f), xpb = make_float4(0.f,0.f,0.f,0.f);
  float hs[8];
  short8 bc[4];
  const int su = q * 64 + lane;      // staging unit for h==1 threads
  const int sr = su >> 4, sk = su & 15;

  #pragma unroll
  for (int t = 0; t < T_HIST; t++) {
    unsigned short* Acur = &Abuf[t & 1][0];
    unsigned short* Anxt = &Abuf[(t & 1) ^ 1][0];

    if (h == 1) {
      if (t < T_HIST - 1) {
        // issue x(t+1) loads early; latency hides under MFMA
        int node = base + sr;
        if (node < N_NODES) {
          const float4* p = (const float4*)&hist[(size_t)node * (T_HIST * HID) + (t + 1) * HID + sk * 8];
          xpa = p[0]; xpb = p[1];
        } else {
          xpa = make_float4(0.f,0.f,0.f,0.f); xpb = make_float4(0.f,0.f,0.f,0.f);
        }
      } else {
        #pragma unroll
        for (int kk = 0; kk < 4; kk++)
          bc[kk] = *(const short8*)&Wc2[(((q & 3) * 4 + kk) * 64 + lane) * 8];
      }
    } else if (t == T_HIST - 1) {
      #pragma unroll
      for (int rb = 0; rb < 2; rb++)
        #pragma unroll
        for (int reg = 0; reg < 4; reg++) {
          int row = rb * 16 + l4 * 4 + reg;
          int node = base + row;
          hs[rb * 4 + reg] = (node < N_NODES) ? hstruct[(size_t)node * HID + jj] : 0.f;
        }
    }

    f32x4 acc[2][2];
    #pragma unroll
    for (int gg = 0; gg < 2; gg++)
      #pragma unroll
      for (int rb = 0; rb < 2; rb++) { f32x4 z = {0.f,0.f,0.f,0.f}; acc[gg][rb] = z; }

    #pragma unroll
    for (int kk = 0; kk < 8; kk++) {
      #pragma unroll
      for (int rb = 0; rb < 2; rb++) {
        int row = rb * 16 + l15;
        int kb = kk * 4 + l4;
        int sb = (kb & 24) | ((kb & 7) ^ (row & 7));
        short8 a = *(const short8*)&Acur[row * 256 + sb * 8];
        acc[0][rb] = __builtin_amdgcn_mfma_f32_16x16x32_bf16(a, Bfr[0][kk], acc[0][rb], 0, 0, 0);
        acc[1][rb] = __builtin_amdgcn_mfma_f32_16x16x32_bf16(a, Bfr[1][kk], acc[1][rb], 0, 0, 0);
      }
    }

    if (h == 1) {
      // publish gates {g,o} (fp32, swizzled quads)
      #pragma unroll
      for (int gg = 0; gg < 2; gg++)
        #pragma unroll
        for (int rb = 0; rb < 2; rb++) {
          int grp = gg * 8 + rb * 4 + l4;
          *(f32x4*)&Gbuf[jj * 64 + ((grp ^ l15) << 2)] = acc[gg][rb];
        }
    }
    __syncthreads();   // G ready

    if (h == 0) {
      f32x4 gq[2], oq[2];
      #pragma unroll
      for (int rb = 0; rb < 2; rb++) {
        gq[rb] = *(const f32x4*)&Gbuf[jj * 64 + (((rb * 4 + l4) ^ l15) << 2)];
        oq[rb] = *(const f32x4*)&Gbuf[jj * 64 + (((8 + rb * 4 + l4) ^ l15) << 2)];
      }
      #pragma unroll
      for (int rb = 0; rb < 2; rb++) {
        #pragma unroll
        for (int reg = 0; reg < 4; reg++) {
          int r = rb * 4 + reg;
          float gi = sigm(acc[0][rb][reg] + bi);
          float gf = sigm(acc[1][rb][reg] + bf_);
          float gg_ = tanh_f(gq[rb][reg] + bg);
          float go = sigm(oq[rb][reg] + bo);
          float c = gf * c_st[r] + gi * gg_;
          c_st[r] = c;
          float hval = go * tanh_f(c);
          int row = rb * 16 + l4 * 4 + reg;
          if (t < T_HIST - 1) {
            int kb = 16 + (jj >> 3);
            int sb = (kb & 24) | ((kb & 7) ^ (row & 7));
            Anxt[row * 256 + sb * 8 + (jj & 7)] = f2bf(hval);
          } else {
            float comb = hs[r] + hval;
            int kb = jj >> 3;
            int sb = (kb & 8) | ((kb & 7) ^ (row & 7));
            Anxt[row * 256 + sb * 8 + (jj & 7)] = f2bf(comb);
          }
        }
      }
    } else if (t < T_HIST - 1) {
      int ssb = (sk & 8) | ((sk & 7) ^ (sr & 7));
      *(short8*)&Anxt[sr * 256 + ssb * 8] = cvt8(xpa, xpb);
    }
    __syncthreads();  // Anxt ready / comb ready
  }

  // classifier: h==1 waves compute the 8 output fragments
  if (h == 1) {
    const unsigned short* Afin = &Abuf[0][0];   // t=7 wrote Anxt = Abuf[0]
    int rbo = q >> 2, cbo = q & 3;
    f32x4 o = {0.f, 0.f, 0.f, 0.f};
    #pragma unroll
    for (int kk = 0; kk < 4; kk++) {
      int row = rbo * 16 + l15;
      int kb = kk * 4 + l4;
      int sb = (kb & 8) | ((kb & 7) ^ (row & 7));
      short8 a = *(const short8*)&Afin[row * 256 + sb * 8];
      o = __builtin_amdgcn_mfma_f32_16x16x32_bf16(a, bc[kk], o, 0, 0, 0);
    }
    int col = cbo * 16 + l15;
    float bcl = b_cls[col];
    #pragma unroll
    for (int reg = 0; reg < 4; reg++) {
      int row = rbo * 16 + l4 * 4 + reg;
      int node = base + row;
      if (node < N_NODES) out[(size_t)node * OUT_DIM + col] = o[reg] + bcl;
    }
  }
}

// ---------------- launch ----------------
extern "C" void kernel_launch(void* const* d_in, const int* in_sizes, int n_in,
                              void* d_out, int out_size, void* d_ws, size_t ws_size,
                              hipStream_t stream) {
  (void)in_sizes; (void)n_in; (void)out_size; (void)ws_size;
  const float* node_feats = (const float*)d_in[0];
  const float* hist       = (const float*)d_in[1];
  const int*   src        = (const int*)d_in[2];
  const int*   dst        = (const int*)d_in[3];
  const float* W_self     = (const float*)d_in[4];
  const float* W_neigh    = (const float*)d_in[5];
  const float* b_sage     = (const float*)d_in[6];
  const float* w_ih       = (const float*)d_in[7];
  const float* w_hh       = (const float*)d_in[8];
  const float* b_lstm     = (const float*)d_in[9];
  const float* W_cls      = (const float*)d_in[10];
  const float* b_cls      = (const float*)d_in[11];
  float* out = (float*)d_out;

  char* ws = (char*)d_ws;
  int* cnt        = (int*)(ws);                    // 200,000 -> 200,192
  int* rowstart   = (int*)(ws + 200192);           // 200,000 -> 400,384
  int* cursor     = (int*)(ws + 400384);           // 200,000 -> 600,576
  int* esrc       = (int*)(ws + 600576);           // 3,200,000 -> 3,800,576
  float* hstruct  = (float*)(ws + 3800576);        // 25,600,000 -> 29,400,576
  unsigned short* Wt2 = (unsigned short*)(ws + 29400576);  // 262,144
  unsigned short* Wc2 = (unsigned short*)(ws + 29662720);  // 16,384

  prepack_kernel<<<64, 256, 0, stream>>>(w_ih, w_hh, W_cls, Wt2, Wc2, cnt);
  count_kernel<<<(N_EDGES + 255) / 256, 256, 0, stream>>>(dst, cnt);
  scan_kernel<<<1, 1024, 0, stream>>>(cnt, rowstart, cursor);
  fill_kernel<<<(N_EDGES + 255) / 256, 256, 0, stream>>>(src, dst, cursor, esrc);
  hstruct_kernel<<<(N_NODES + HS_TILE - 1) / HS_TILE, 512, 0, stream>>>(
      node_feats, esrc, rowstart, cnt, W_self, W_neigh, b_sage, hstruct);
  lstm_kernel<<<(N_NODES + LB - 1) / LB, 1024, 0, stream>>>(
      hist, Wt2, Wc2, b_lstm, hstruct, b_cls, out);
}

// Round 6
// 471.073 us; speedup vs baseline: 1.3976x; 1.3976x over previous
//
#include <hip/hip_runtime.h>
#include <hip/hip_bf16.h>
#include <stdint.h>

#define N_NODES 50000
#define N_EDGES 800000
#define IN_DIM 64
#define HID 128
#define OUT_DIM 64
#define T_HIST 8

typedef __attribute__((ext_vector_type(8))) short short8;
typedef __attribute__((ext_vector_type(4))) float f32x4;

__device__ __forceinline__ unsigned short f2bf(float x) {
  unsigned int u = __builtin_bit_cast(unsigned int, x);
  unsigned int r = (u + 0x7FFFu + ((u >> 16) & 1u)) >> 16;
  return (unsigned short)r;
}
__device__ __forceinline__ short8 cvt8(float4 a, float4 b) {
  unsigned int w0, w1, w2, w3;
  asm("v_cvt_pk_bf16_f32 %0, %1, %2" : "=v"(w0) : "v"(a.x), "v"(a.y));
  asm("v_cvt_pk_bf16_f32 %0, %1, %2" : "=v"(w1) : "v"(a.z), "v"(a.w));
  asm("v_cvt_pk_bf16_f32 %0, %1, %2" : "=v"(w2) : "v"(b.x), "v"(b.y));
  asm("v_cvt_pk_bf16_f32 %0, %1, %2" : "=v"(w3) : "v"(b.z), "v"(b.w));
  struct { unsigned int a, b, c, d; } s{w0, w1, w2, w3};
  return __builtin_bit_cast(short8, s);
}
// sigmoid/tanh via exp2+rcp; safe at +-inf
__device__ __forceinline__ float sigm(float x) {
  float e = __builtin_amdgcn_exp2f(-1.4426950408889634f * x);
  return __builtin_amdgcn_rcpf(1.f + e);
}
__device__ __forceinline__ float tanh_f(float x) {
  float e = __builtin_amdgcn_exp2f(2.8853900817779268f * x);
  return 1.f - 2.f * __builtin_amdgcn_rcpf(e + 1.f);
}

// ---------------- prepack: bf16 frag weights + folded classifier weights + cnt zero ----------------
// Wt2: F = q*32 + g*8 + kk; value = Wcomb[k = kk*32+(lane>>4)*8+i][c = g*128 + q*16 + (lane&15)]
// Wc2: F = cb*4 + kk; value = W_cls[k][col = cb*16 + (lane&15)]
// Wsc = W_self@W_cls [64][64]; Wnc = W_neigh@W_cls; bc1 = b_sage@W_cls + b_cls
__global__ void prepack_kernel(const float* __restrict__ w_ih, const float* __restrict__ w_hh,
                               const float* __restrict__ W_cls,
                               const float* __restrict__ W_self, const float* __restrict__ W_neigh,
                               const float* __restrict__ b_sage, const float* __restrict__ b_cls,
                               unsigned short* __restrict__ Wt2, unsigned short* __restrict__ Wc2,
                               float* __restrict__ Wsc, float* __restrict__ Wnc,
                               float* __restrict__ bc1, int* __restrict__ cnt) {
  int tid = blockIdx.x * blockDim.x + threadIdx.x;
  int stride = gridDim.x * blockDim.x;
  for (int i = tid; i < N_NODES; i += stride) cnt[i] = 0;
  for (int idx = tid; idx < 256 * 512; idx += stride) {
    int i = idx & 7;
    int lane = (idx >> 3) & 63;
    int F = idx >> 9;
    int q = F >> 5, g = (F >> 3) & 3, kk = F & 7;
    int c = g * 128 + q * 16 + (lane & 15);
    int k = kk * 32 + (lane >> 4) * 8 + i;
    float v = (k < 128) ? w_ih[k * 512 + c] : w_hh[(k - 128) * 512 + c];
    Wt2[idx] = f2bf(v);
  }
  for (int idx = tid; idx < 16 * 512; idx += stride) {
    int i = idx & 7;
    int lane = (idx >> 3) & 63;
    int F = idx >> 9;
    int cb = F >> 2, kk = F & 3;
    int col = cb * 16 + (lane & 15);
    int k = kk * 32 + (lane >> 4) * 8 + i;
    Wc2[idx] = f2bf(W_cls[k * 64 + col]);
  }
  for (int idx = tid; idx < 64 * 64; idx += stride) {
    int k = idx >> 6, c = idx & 63;
    float as = 0.f, an = 0.f;
    for (int m = 0; m < 128; m++) {
      float wc = W_cls[m * 64 + c];
      as += W_self[k * 128 + m] * wc;
      an += W_neigh[k * 128 + m] * wc;
    }
    Wsc[idx] = as;
    Wnc[idx] = an;
  }
  for (int c = tid; c < 64; c += stride) {
    float acc = b_cls[c];
    for (int m = 0; m < 128; m++) acc += b_sage[m] * W_cls[m * 64 + c];
    bc1[c] = acc;
  }
}

// ---------------- CSR build ----------------
__global__ void count_kernel(const int* __restrict__ dst, int* __restrict__ cnt) {
  int e = blockIdx.x * blockDim.x + threadIdx.x;
  if (e < N_EDGES) atomicAdd(&cnt[dst[e]], 1);
}

// fused scan: single block, 1024 threads, chunk 49
__global__ __launch_bounds__(1024) void scan_kernel(const int* __restrict__ cnt,
                                                    int* __restrict__ rowstart,
                                                    int* __restrict__ cursor) {
  __shared__ int sh[1024];
  int tid = threadIdx.x;
  const int C = 49;
  int b0 = tid * C;
  int tsum = 0;
  for (int j = 0; j < C; j++) {
    int i = b0 + j;
    if (i < N_NODES) tsum += cnt[i];
  }
  sh[tid] = tsum;
  __syncthreads();
  int val = tsum;
  for (int off = 1; off < 1024; off <<= 1) {
    int x = (tid >= off) ? sh[tid - off] : 0;
    __syncthreads();
    val += x;
    sh[tid] = val;
    __syncthreads();
  }
  int run = val - tsum;  // exclusive prefix
  for (int j = 0; j < C; j++) {
    int i = b0 + j;
    if (i < N_NODES) { rowstart[i] = run; cursor[i] = run; run += cnt[i]; }
  }
}

__global__ void fill_kernel(const int* __restrict__ src, const int* __restrict__ dst,
                            int* __restrict__ cursor, int* __restrict__ esrc) {
  int e = blockIdx.x * blockDim.x + threadIdx.x;
  if (e < N_EDGES) {
    int d = dst[e];
    int pos = atomicAdd(&cursor[d], 1);
    esrc[pos] = src[e];
  }
}

// ---------------- out1 = (nf@Wself + mean_neigh@Wneigh + b_sage)@W_cls + b_cls
//                       = nf@Wsc + mean_neigh@Wnc + bc1   (weights pre-folded) ----------------
#define HS_TILE 32
__global__ __launch_bounds__(256) void hstruct_kernel(
    const float* __restrict__ nf, const int* __restrict__ esrc,
    const int* __restrict__ rowstart, const int* __restrict__ cnt,
    const float* __restrict__ Wsc, const float* __restrict__ Wnc, const float* __restrict__ bc1,
    float* __restrict__ out1) {
  __shared__ float s_nf[HS_TILE][IN_DIM + 1];
  __shared__ float s_hn[HS_TILE][IN_DIM + 1];
  int tid = threadIdx.x;
  int node0 = blockIdx.x * HS_TILE;
  for (int i = tid; i < HS_TILE * IN_DIM; i += 256) {
    int r = i >> 6, k = i & 63;
    int node = node0 + r;
    s_nf[r][k] = (node < N_NODES) ? nf[node * 64 + k] : 0.f;
  }
  int wv = tid >> 6, lane = tid & 63;
  for (int r = wv; r < HS_TILE; r += 4) {
    int node = node0 + r;
    float a0 = 0.f, a1 = 0.f, a2 = 0.f, a3 = 0.f;
    int n = 0;
    if (node < N_NODES) {
      n = cnt[node];
      int st = rowstart[node];
      int j = 0;
      for (; j + 4 <= n; j += 4) {
        int s0 = esrc[st + j], s1 = esrc[st + j + 1];
        int s2 = esrc[st + j + 2], s3 = esrc[st + j + 3];
        a0 += nf[s0 * 64 + lane];
        a1 += nf[s1 * 64 + lane];
        a2 += nf[s2 * 64 + lane];
        a3 += nf[s3 * 64 + lane];
      }
      for (; j < n; j++) a0 += nf[esrc[st + j] * 64 + lane];
    }
    s_hn[r][lane] = (a0 + a1 + a2 + a3) * __builtin_amdgcn_rcpf(fmaxf((float)n, 1.f));
  }
  __syncthreads();
  int r = tid & 31;
  int c0 = (tid >> 5) * 8;   // 8 col-groups x 8 cols = 64
  float accs[8];
  #pragma unroll
  for (int i = 0; i < 8; i++) accs[i] = 0.f;
  for (int k = 0; k < IN_DIM; k++) {
    float a = s_nf[r][k];
    float b = s_hn[r][k];
    const float4* ws = (const float4*)&Wsc[k * 64 + c0];
    const float4* wn = (const float4*)&Wnc[k * 64 + c0];
    #pragma unroll
    for (int q2 = 0; q2 < 2; q2++) {
      float4 w1 = ws[q2]; float4 w2 = wn[q2];
      accs[q2*4+0] += a * w1.x + b * w2.x;
      accs[q2*4+1] += a * w1.y + b * w2.y;
      accs[q2*4+2] += a * w1.z + b * w2.z;
      accs[q2*4+3] += a * w1.w + b * w2.w;
    }
  }
  int node = node0 + r;
  if (node < N_NODES) {
    #pragma unroll
    for (int i = 0; i < 8; i++)
      out1[(size_t)node * 64 + c0 + i] = accs[i] + bc1[c0 + i];
  }
}

// ---------------- fused LSTM (8 steps) + classifier, W in registers ----------------
// R4-proven structure: 512 thr = 8 waves, 64 nodes/block, wave owns 16 cols x 4 gates,
// 4 row-block passes (acc stays 16 regs), double-buffered A, 1 barrier/step.
// Epilogue simplified: out = h_temp@W_cls + out1 (hstruct gather eliminated).
#define LB 64
__global__ __launch_bounds__(512, 2) void lstm_kernel(
    const float* __restrict__ hist,          // [N][8][128] f32
    const unsigned short* __restrict__ Wt2,  // frag-ordered bf16
    const unsigned short* __restrict__ Wc2,  // frag-ordered bf16
    const float* __restrict__ b_lstm,        // [512]
    const float* __restrict__ out1,          // [N][64] fp32 (classifier partial)
    float* __restrict__ out)                 // [N][64]
{
  __shared__ alignas(16) unsigned short Abuf[2][64 * 256];  // 2 x 32KB, [row][swz(kb)][8]

  const int tid = threadIdx.x;
  const int lane = tid & 63;
  const int w = tid >> 6;
  const int l15 = lane & 15;
  const int l4 = lane >> 4;
  const int base = blockIdx.x * LB;
  const int jj = w * 16 + l15;     // hidden unit owned by this lane

  // persistent B fragments: Bfr[g][kk]  (128 VGPR)
  short8 Bfr[4][8];
  #pragma unroll
  for (int g = 0; g < 4; g++)
    #pragma unroll
    for (int kk = 0; kk < 8; kk++)
      Bfr[g][kk] = *(const short8*)&Wt2[((w * 32 + g * 8 + kk) * 64 + lane) * 8];

  const float bi  = b_lstm[jj];
  const float bf_ = b_lstm[128 + jj];
  const float bg  = b_lstm[256 + jj];
  const float bo  = b_lstm[384 + jj];

  float c_st[16];
  #pragma unroll
  for (int i = 0; i < 16; i++) c_st[i] = 0.f;

  // prologue: zero h-region of buf0, stage x(0) into buf0
  for (int u = tid; u < 64 * 16; u += 512) {
    int row = u >> 4;
    int kbh = u & 15;
    short8 z = {0,0,0,0,0,0,0,0};
    *(short8*)&Abuf[0][row * 256 + 128 + kbh * 8] = z;
  }
  #pragma unroll
  for (int i2 = 0; i2 < 2; i2++) {
    int u = tid + (i2 << 9);
    int row = u >> 4;
    int kb = u & 15;
    int node = base + row;
    float4 x0 = make_float4(0.f,0.f,0.f,0.f), x1 = make_float4(0.f,0.f,0.f,0.f);
    if (node < N_NODES) {
      const float4* p = (const float4*)&hist[(size_t)node * (T_HIST * HID) + kb * 8];
      x0 = p[0]; x1 = p[1];
    }
    int sb = (kb & 8) | ((kb & 7) ^ (row & 7));
    *(short8*)&Abuf[0][row * 256 + sb * 8] = cvt8(x0, x1);
  }
  __syncthreads();

  float4 xp[4];  // prefetch regs (16 VGPR)

  // ---- steps 0..6 ----
  #pragma unroll
  for (int t = 0; t < T_HIST - 1; t++) {
    unsigned short* Acur = &Abuf[t & 1][0];
    unsigned short* Anxt = &Abuf[(t & 1) ^ 1][0];

    // issue x(t+1) global loads early: latency hides under MFMA phase
    #pragma unroll
    for (int i2 = 0; i2 < 2; i2++) {
      int u = tid + (i2 << 9);
      int row = u >> 4;
      int kb = u & 15;
      int node = base + row;
      if (node < N_NODES) {
        const float4* p = (const float4*)&hist[(size_t)node * (T_HIST * HID) + (t + 1) * HID + kb * 8];
        xp[i2 * 2]     = p[0];
        xp[i2 * 2 + 1] = p[1];
      } else {
        xp[i2 * 2]     = make_float4(0.f,0.f,0.f,0.f);
        xp[i2 * 2 + 1] = make_float4(0.f,0.f,0.f,0.f);
      }
    }

    // 4 row-block passes; acc (16 VGPR) dies at end of each pass
    #pragma unroll
    for (int rb = 0; rb < 4; rb++) {
      f32x4 acc[4];
      #pragma unroll
      for (int g = 0; g < 4; g++) { f32x4 z = {0.f,0.f,0.f,0.f}; acc[g] = z; }
      #pragma unroll
      for (int kk = 0; kk < 8; kk++) {
        int row = rb * 16 + l15;
        int kb = kk * 4 + l4;
        int sb = (kb & 24) | ((kb & 7) ^ (row & 7));
        short8 a = *(const short8*)&Acur[row * 256 + sb * 8];
        #pragma unroll
        for (int g = 0; g < 4; g++)
          acc[g] = __builtin_amdgcn_mfma_f32_16x16x32_bf16(a, Bfr[g][kk], acc[g], 0, 0, 0);
      }
      // cell update for this row block; h -> Anxt h-region
      #pragma unroll
      for (int reg = 0; reg < 4; reg++) {
        int r = rb * 4 + reg;
        float gi = sigm(acc[0][reg] + bi);
        float gf = sigm(acc[1][reg] + bf_);
        float gg = tanh_f(acc[2][reg] + bg);
        float go = sigm(acc[3][reg] + bo);
        float c = gf * c_st[r] + gi * gg;
        c_st[r] = c;
        float h = go * tanh_f(c);
        int row = rb * 16 + l4 * 4 + reg;
        int kb = 16 + (jj >> 3);
        int sb = (kb & 24) | ((kb & 7) ^ (row & 7));
        Anxt[row * 256 + sb * 8 + (jj & 7)] = f2bf(h);
      }
      __builtin_amdgcn_sched_barrier(0);  // keep passes separate: acc stays 16 regs
    }

    // write staged x(t+1) into next buffer's x-region
    #pragma unroll
    for (int i2 = 0; i2 < 2; i2++) {
      int u = tid + (i2 << 9);
      int row = u >> 4;
      int kb = u & 15;
      int sb = (kb & 8) | ((kb & 7) ^ (row & 7));
      *(short8*)&Anxt[row * 256 + sb * 8] = cvt8(xp[i2 * 2], xp[i2 * 2 + 1]);
    }
    __syncthreads();   // single barrier per step
  }

  // ---- t = 7 (peeled): final step; write h into x-region of Abuf[0] ----
  {
    unsigned short* Acur = &Abuf[1][0];
    unsigned short* Anxt = &Abuf[0][0];

    #pragma unroll
    for (int rb = 0; rb < 4; rb++) {
      f32x4 acc[4];
      #pragma unroll
      for (int g = 0; g < 4; g++) { f32x4 z = {0.f,0.f,0.f,0.f}; acc[g] = z; }
      #pragma unroll
      for (int kk = 0; kk < 8; kk++) {
        int row = rb * 16 + l15;
        int kb = kk * 4 + l4;
        int sb = (kb & 24) | ((kb & 7) ^ (row & 7));
        short8 a = *(const short8*)&Acur[row * 256 + sb * 8];
        #pragma unroll
        for (int g = 0; g < 4; g++)
          acc[g] = __builtin_amdgcn_mfma_f32_16x16x32_bf16(a, Bfr[g][kk], acc[g], 0, 0, 0);
      }
      #pragma unroll
      for (int reg = 0; reg < 4; reg++) {
        int r = rb * 4 + reg;
        float gi = sigm(acc[0][reg] + bi);
        float gf = sigm(acc[1][reg] + bf_);
        float gg = tanh_f(acc[2][reg] + bg);
        float go = sigm(acc[3][reg] + bo);
        float c = gf * c_st[r] + gi * gg;
        float h = go * tanh_f(c);
        int row = rb * 16 + l4 * 4 + reg;
        int kb = jj >> 3;
        int sb = (kb & 8) | ((kb & 7) ^ (row & 7));
        Anxt[row * 256 + sb * 8 + (jj & 7)] = f2bf(h);
      }
      __builtin_amdgcn_sched_barrier(0);
    }
    __syncthreads();

    // classifier: out = h_temp @ W_cls + out1   (Bfr dead -> bc loads here)
    #pragma unroll
    for (int fi = 0; fi < 2; fi++) {
      int f = w * 2 + fi;
      int rbo = f >> 2, cbo = f & 3;
      int col = cbo * 16 + l15;
      // preload out1 partials (coalesced) + W_cls frags
      float ov[4];
      #pragma unroll
      for (int reg = 0; reg < 4; reg++) {
        int row = rbo * 16 + l4 * 4 + reg;
        int node = base + row;
        ov[reg] = (node < N_NODES) ? out1[(size_t)node * OUT_DIM + col] : 0.f;
      }
      f32x4 o = {0.f, 0.f, 0.f, 0.f};
      #pragma unroll
      for (int kk = 0; kk < 4; kk++) {
        short8 bv = *(const short8*)&Wc2[((cbo * 4 + kk) * 64 + lane) * 8];
        int row = rbo * 16 + l15;
        int kb = kk * 4 + l4;
        int sb = (kb & 8) | ((kb & 7) ^ (row & 7));
        short8 a = *(const short8*)&Anxt[row * 256 + sb * 8];
        o = __builtin_amdgcn_mfma_f32_16x16x32_bf16(a, bv, o, 0, 0, 0);
      }
      #pragma unroll
      for (int reg = 0; reg < 4; reg++) {
        int row = rbo * 16 + l4 * 4 + reg;
        int node = base + row;
        if (node < N_NODES) out[(size_t)node * OUT_DIM + col] = o[reg] + ov[reg];
      }
    }
  }
}

// ---------------- launch ----------------
extern "C" void kernel_launch(void* const* d_in, const int* in_sizes, int n_in,
                              void* d_out, int out_size, void* d_ws, size_t ws_size,
                              hipStream_t stream) {
  (void)in_sizes; (void)n_in; (void)out_size; (void)ws_size;
  const float* node_feats = (const float*)d_in[0];
  const float* hist       = (const float*)d_in[1];
  const int*   src        = (const int*)d_in[2];
  const int*   dst        = (const int*)d_in[3];
  const float* W_self     = (const float*)d_in[4];
  const float* W_neigh    = (const float*)d_in[5];
  const float* b_sage     = (const float*)d_in[6];
  const float* w_ih       = (const float*)d_in[7];
  const float* w_hh       = (const float*)d_in[8];
  const float* b_lstm     = (const float*)d_in[9];
  const float* W_cls      = (const float*)d_in[10];
  const float* b_cls      = (const float*)d_in[11];
  float* out = (float*)d_out;

  char* ws = (char*)d_ws;
  int* cnt        = (int*)(ws);                        // 200,000 -> 200,192
  int* rowstart   = (int*)(ws + 200192);               // 200,000 -> 400,384
  int* cursor     = (int*)(ws + 400384);               // 200,000 -> 600,576
  int* esrc       = (int*)(ws + 600576);               // 3,200,000 -> 3,800,576
  float* out1     = (float*)(ws + 3800576);            // 12,800,000 -> 16,600,576
  unsigned short* Wt2 = (unsigned short*)(ws + 16600576);  // 262,144 -> 16,862,720
  unsigned short* Wc2 = (unsigned short*)(ws + 16862720);  // 16,384 -> 16,879,104
  float* Wsc      = (float*)(ws + 16879104);           // 16,384 -> 16,895,488
  float* Wnc      = (float*)(ws + 16895488);           // 16,384 -> 16,911,872
  float* bc1      = (float*)(ws + 16911872);           // 256

  prepack_kernel<<<128, 256, 0, stream>>>(w_ih, w_hh, W_cls, W_self, W_neigh, b_sage, b_cls,
                                          Wt2, Wc2, Wsc, Wnc, bc1, cnt);
  count_kernel<<<(N_EDGES + 255) / 256, 256, 0, stream>>>(dst, cnt);
  scan_kernel<<<1, 1024, 0, stream>>>(cnt, rowstart, cursor);
  fill_kernel<<<(N_EDGES + 255) / 256, 256, 0, stream>>>(src, dst, cursor, esrc);
  hstruct_kernel<<<(N_NODES + HS_TILE - 1) / HS_TILE, 256, 0, stream>>>(
      node_feats, esrc, rowstart, cnt, Wsc, Wnc, bc1, out1);
  lstm_kernel<<<(N_NODES + LB - 1) / LB, 512, 0, stream>>>(
      hist, Wt2, Wc2, b_lstm, out1, out);
}